// Round 1
// baseline (204.100 us; speedup 1.0000x reference)
//
#include <hip/hip_runtime.h>

// Causal flash-attention forward, B=2 L=2048 H=16 E=D=64, fp32 in/out.
// bf16 MFMA (16x16x32) with fp32 accumulation; online softmax.

using f32x4  = __attribute__((ext_vector_type(4))) float;
using bf16x8 = __attribute__((ext_vector_type(8))) short;

constexpr int L = 2048;
constexpr int H = 16;
constexpr int E = 64;          // head dim (= D)
constexpr int QBLK = 64;       // q rows per block (16 per wave)
constexpr int KVBLK = 64;      // kv rows per tile
constexpr float SCALE = 0.125f;        // 1/sqrt(64), exact power of 2
constexpr float LOG2E = 1.44269504088896f;

// fp32 -> bf16 round-to-nearest-even
__device__ __forceinline__ short f2bf(float f) {
    unsigned u = __float_as_uint(f);
    u += 0x7fffu + ((u >> 16) & 1u);
    return (short)(u >> 16);
}

// XOR swizzle for a 128-byte row: permutes 16B chunks by row&7
// (breaks the stride-128B same-bank pattern; reads/writes stay 16B-aligned)
__device__ __forceinline__ int swz(int row, int bcol) {
    return (row * 128 + bcol) ^ ((row & 7) << 4);
}

__global__ __launch_bounds__(256)
void fattn_kernel(const float* __restrict__ Q,
                  const float* __restrict__ K,
                  const float* __restrict__ V,
                  float* __restrict__ O)
{
    __shared__ short Kl[KVBLK * 64];   // [s][e], swizzled rows (128B each)
    __shared__ short Vl[64 * KVBLK];   // [d][s], swizzled rows (transposed V)
    __shared__ short Pl[4][16 * 64];   // per-wave P tile [r][s], swizzled

    const int bx   = blockIdx.x;
    const int iq   = bx & 31;          // q-tile index (L/QBLK = 32)
    const int bh   = bx >> 5;
    const int h    = bh & 15;
    const int b    = bh >> 4;
    const int tid  = threadIdx.x;
    const int w    = tid >> 6;
    const int lane = tid & 63;
    const int l16  = lane & 15;
    const int lhi  = lane >> 4;

    const int qbase = iq * QBLK;
    const size_t bhoff = (size_t)b * L * (H * E) + (size_t)h * E;
    const int rowstride = H * E;       // 1024 floats between consecutive l

    // ---- load Q fragments (A-operand layout), scale folded in ----
    // A frag for 16x16x32: lane holds row = lane&15, k = (lane>>4)*8 + i (+32*kf)
    bf16x8 qf[2];
    {
        const int qrow = qbase + w * 16 + l16;
        const float* qp = Q + bhoff + (size_t)qrow * rowstride + lhi * 8;
        #pragma unroll
        for (int kf = 0; kf < 2; ++kf) {
            float4 x = *(const float4*)(qp + kf * 32);
            float4 y = *(const float4*)(qp + kf * 32 + 4);
            bf16x8 t;
            t[0] = f2bf(x.x * SCALE); t[1] = f2bf(x.y * SCALE);
            t[2] = f2bf(x.z * SCALE); t[3] = f2bf(x.w * SCALE);
            t[4] = f2bf(y.x * SCALE); t[5] = f2bf(y.y * SCALE);
            t[6] = f2bf(y.z * SCALE); t[7] = f2bf(y.w * SCALE);
            qf[kf] = t;
        }
    }

    // ---- online-softmax state: this lane covers rows (lhi*4 + r), r=0..3 ----
    float m[4], lsum[4];
    f32x4 oacc[4];
    #pragma unroll
    for (int r = 0; r < 4; ++r) { m[r] = -INFINITY; lsum[r] = 0.0f; }
    #pragma unroll
    for (int dt = 0; dt < 4; ++dt) oacc[dt] = (f32x4){0.f, 0.f, 0.f, 0.f};

    const int nkv = iq + 1;
    for (int t = 0; t < nkv; ++t) {
        const int sbase = t * KVBLK;
        __syncthreads();   // protect Vl/Kl reuse from previous iteration

        // ---- stage K [s][e] and V transposed [d][s] into LDS ----
        #pragma unroll
        for (int g = 0; g < 2; ++g) {
            const int c  = g * 256 + tid;     // chunk 0..511
            const int s  = c >> 3;
            const int e0 = (c & 7) * 8;
            const float* kp = K + bhoff + (size_t)(sbase + s) * rowstride + e0;
            float4 kx = *(const float4*)kp;
            float4 ky = *(const float4*)(kp + 4);
            bf16x8 kt;
            kt[0] = f2bf(kx.x); kt[1] = f2bf(kx.y); kt[2] = f2bf(kx.z); kt[3] = f2bf(kx.w);
            kt[4] = f2bf(ky.x); kt[5] = f2bf(ky.y); kt[6] = f2bf(ky.z); kt[7] = f2bf(ky.w);
            *(bf16x8*)((char*)Kl + swz(s, e0 * 2)) = kt;

            const float* vp = V + bhoff + (size_t)(sbase + s) * rowstride + e0;
            float4 vx = *(const float4*)vp;
            float4 vy = *(const float4*)(vp + 4);
            float vv[8] = {vx.x, vx.y, vx.z, vx.w, vy.x, vy.y, vy.z, vy.w};
            #pragma unroll
            for (int j = 0; j < 8; ++j)   // transpose scatter: d = e0+j, col s
                *(short*)((char*)Vl + swz(e0 + j, s * 2)) = f2bf(vv[j]);
        }
        __syncthreads();

        // ---- S = Q K^T : 4 col-tiles x (K=64 -> 2 MFMA) ----
        f32x4 sacc[4];
        #pragma unroll
        for (int ct = 0; ct < 4; ++ct) sacc[ct] = (f32x4){0.f, 0.f, 0.f, 0.f};
        #pragma unroll
        for (int ct = 0; ct < 4; ++ct) {
            const int srow = ct * 16 + l16;   // B-operand: col = lane&15 -> kv row
            #pragma unroll
            for (int kf = 0; kf < 2; ++kf) {
                bf16x8 bf = *(const bf16x8*)((char*)Kl + swz(srow, (lhi * 8 + kf * 32) * 2));
                sacc[ct] = __builtin_amdgcn_mfma_f32_16x16x32_bf16(qf[kf], bf, sacc[ct], 0, 0, 0);
            }
        }

        // ---- causal mask (diagonal tile only) ----
        if (t == nkv - 1) {
            #pragma unroll
            for (int ct = 0; ct < 4; ++ct) {
                const int sg = sbase + ct * 16 + l16;
                #pragma unroll
                for (int r = 0; r < 4; ++r) {
                    const int qg = qbase + w * 16 + lhi * 4 + r;
                    if (sg > qg) sacc[ct][r] = -INFINITY;
                }
            }
        }

        // ---- online softmax (rows = lhi*4 + r, reduce across 16-lane group) ----
        float corr[4];
        #pragma unroll
        for (int r = 0; r < 4; ++r) {
            float v = fmaxf(fmaxf(sacc[0][r], sacc[1][r]),
                            fmaxf(sacc[2][r], sacc[3][r]));
            v = fmaxf(v, __shfl_xor(v, 1));
            v = fmaxf(v, __shfl_xor(v, 2));
            v = fmaxf(v, __shfl_xor(v, 4));
            v = fmaxf(v, __shfl_xor(v, 8));
            const float mn = fmaxf(m[r], v);
            corr[r] = exp2f((m[r] - mn) * LOG2E);
            m[r] = mn;
        }
        float rs[4] = {0.f, 0.f, 0.f, 0.f};
        #pragma unroll
        for (int ct = 0; ct < 4; ++ct) {
            #pragma unroll
            for (int r = 0; r < 4; ++r) {
                const float p = exp2f((sacc[ct][r] - m[r]) * LOG2E);
                sacc[ct][r] = p;
                rs[r] += p;
            }
        }
        #pragma unroll
        for (int r = 0; r < 4; ++r) {
            float v = rs[r];
            v += __shfl_xor(v, 1);
            v += __shfl_xor(v, 2);
            v += __shfl_xor(v, 4);
            v += __shfl_xor(v, 8);
            lsum[r] = lsum[r] * corr[r] + v;
        }
        #pragma unroll
        for (int dt = 0; dt < 4; ++dt)
            #pragma unroll
            for (int r = 0; r < 4; ++r) oacc[dt][r] *= corr[r];

        // ---- P: C-layout -> A-layout via per-wave LDS round trip ----
        char* pw = (char*)Pl[w];
        #pragma unroll
        for (int ct = 0; ct < 4; ++ct)
            #pragma unroll
            for (int r = 0; r < 4; ++r)
                *(short*)(pw + swz(lhi * 4 + r, (ct * 16 + l16) * 2)) = f2bf(sacc[ct][r]);
        asm volatile("s_waitcnt lgkmcnt(0)" ::: "memory");
        bf16x8 pa[2];
        #pragma unroll
        for (int kf = 0; kf < 2; ++kf)
            pa[kf] = *(const bf16x8*)(pw + swz(l16, (lhi * 8 + kf * 32) * 2));

        // ---- O += P V : B-operand from transposed V_lds ----
        #pragma unroll
        for (int dt = 0; dt < 4; ++dt) {
            const int vrow = dt * 16 + l16;   // d index
            #pragma unroll
            for (int kf = 0; kf < 2; ++kf) {
                bf16x8 bf = *(const bf16x8*)((char*)Vl + swz(vrow, (lhi * 8 + kf * 32) * 2));
                oacc[dt] = __builtin_amdgcn_mfma_f32_16x16x32_bf16(pa[kf], bf, oacc[dt], 0, 0, 0);
            }
        }
    }

    // ---- epilogue: normalize and store fp32 ----
    float inv[4];
    #pragma unroll
    for (int r = 0; r < 4; ++r) inv[r] = 1.0f / lsum[r];
    #pragma unroll
    for (int dt = 0; dt < 4; ++dt) {
        #pragma unroll
        for (int r = 0; r < 4; ++r) {
            const int qg = qbase + w * 16 + lhi * 4 + r;
            O[bhoff + (size_t)qg * rowstride + dt * 16 + l16] = oacc[dt][r] * inv[r];
        }
    }
}

extern "C" void kernel_launch(void* const* d_in, const int* in_sizes, int n_in,
                              void* d_out, int out_size, void* d_ws, size_t ws_size,
                              hipStream_t stream) {
    const float* Q = (const float*)d_in[0];
    const float* K = (const float*)d_in[1];
    const float* V = (const float*)d_in[2];
    float* O = (float*)d_out;
    const int B = 2;
    dim3 grid((L / QBLK) * B * H);   // 32 q-tiles * 32 (b,h) = 1024 blocks
    dim3 block(256);
    fattn_kernel<<<grid, block, 0, stream>>>(Q, K, V, O);
}

// Round 2
// 87.780 us; speedup vs baseline: 2.3251x; 2.3251x over previous
//
#include <hip/hip_runtime.h>

// Causal flash-attention forward, B=2 L=2048 H=16 E=D=64, fp32 in/out.
// bf16 MFMA (16x16x32) with fp32 accumulation; online softmax (log2 domain).
// R2: register-prefetch staging, conflict-free V-transpose swizzle,
//     balanced + XCD-aware block remap.

using f32x4  = __attribute__((ext_vector_type(4))) float;
using bf16x8 = __attribute__((ext_vector_type(8))) short;

constexpr int L = 2048;
constexpr int H = 16;
constexpr int E = 64;          // head dim (= D)
constexpr int QBLK = 64;       // q rows per block (16 per wave)
constexpr int KVBLK = 64;      // kv rows per tile
// scale * log2(e): softmax runs in exp2 domain, scale folded into Q cast
constexpr float QSC = 0.125f * 1.44269504088896f;

// fp32 -> bf16 round-to-nearest-even
__device__ __forceinline__ short f2bf(float f) {
    unsigned u = __float_as_uint(f);
    u += 0x7fffu + ((u >> 16) & 1u);
    return (short)(u >> 16);
}

// XOR swizzle for 128-byte rows (K, P tiles): permute 16B chunks by row&7
__device__ __forceinline__ int swz(int row, int bcol) {
    return (row * 128 + bcol) ^ ((row & 7) << 4);
}
// V-transpose swizzle: also mix row>>3 so the 8 lanes sharing a column land
// in 8 distinct bank groups on the b16 scatter; reads stay 16B-aligned.
__device__ __forceinline__ int swzV(int row, int bcol) {
    return (row * 128 + bcol) ^ ((((row & 7) ^ (row >> 3)) & 7) << 4);
}

__global__ __launch_bounds__(256)
void fattn_kernel(const float* __restrict__ Q,
                  const float* __restrict__ K,
                  const float* __restrict__ V,
                  float* __restrict__ O)
{
    __shared__ short Kl[KVBLK * 64];   // [s][e], swizzled rows
    __shared__ short Vl[64 * KVBLK];   // [d][s], swizzled rows (transposed V)
    __shared__ short Pl[4][16 * 64];   // per-wave P tile [r][s], swizzled

    // ---- balanced, XCD-aware block remap ----
    // xcd = bx&7 (HW round-robins XCDs by dispatch index); all q-tiles of one
    // (b,h) land on the same XCD; per-CU work sums to exactly 66 tile-iters.
    const int bx  = blockIdx.x;
    const int xcd = bx & 7;
    const int j   = bx >> 3;             // 0..127
    const int bh  = (j & 3) * 8 + xcd;   // 0..31
    const int v_  = j >> 2;              // 0..31
    const int iq  = (v_ < 16) ? v_ : 47 - v_;
    const int h    = bh & 15;
    const int b    = bh >> 4;
    const int tid  = threadIdx.x;
    const int w    = tid >> 6;
    const int lane = tid & 63;
    const int l16  = lane & 15;
    const int lhi  = lane >> 4;

    const int qbase = iq * QBLK;
    const size_t bhoff = (size_t)b * L * (H * E) + (size_t)h * E;
    const int rowstride = H * E;       // 1024 floats between consecutive l

    // ---- load Q fragments (A-operand layout), scale*log2e folded in ----
    bf16x8 qf[2];
    {
        const int qrow = qbase + w * 16 + l16;
        const float* qp = Q + bhoff + (size_t)qrow * rowstride + lhi * 8;
        #pragma unroll
        for (int kf = 0; kf < 2; ++kf) {
            float4 x = *(const float4*)(qp + kf * 32);
            float4 y = *(const float4*)(qp + kf * 32 + 4);
            bf16x8 t;
            t[0] = f2bf(x.x * QSC); t[1] = f2bf(x.y * QSC);
            t[2] = f2bf(x.z * QSC); t[3] = f2bf(x.w * QSC);
            t[4] = f2bf(y.x * QSC); t[5] = f2bf(y.y * QSC);
            t[6] = f2bf(y.z * QSC); t[7] = f2bf(y.w * QSC);
            qf[kf] = t;
        }
    }

    // ---- per-thread staging coords ----
    // chunk c = g*256 + tid: s = c>>3, e0 = (c&7)*8
    float4 kxr[2], kyr[2], vxr[2], vyr[2];   // prefetch registers

    auto issue_loads = [&](int t) {
        const int sbase = t * KVBLK;
        #pragma unroll
        for (int g = 0; g < 2; ++g) {
            const int c  = g * 256 + tid;
            const int s  = c >> 3;
            const int e0 = (c & 7) * 8;
            const float* kp = K + bhoff + (size_t)(sbase + s) * rowstride + e0;
            kxr[g] = *(const float4*)kp;
            kyr[g] = *(const float4*)(kp + 4);
            const float* vp = V + bhoff + (size_t)(sbase + s) * rowstride + e0;
            vxr[g] = *(const float4*)vp;
            vyr[g] = *(const float4*)(vp + 4);
        }
    };
    auto write_lds = [&]() {
        #pragma unroll
        for (int g = 0; g < 2; ++g) {
            const int c  = g * 256 + tid;
            const int s  = c >> 3;
            const int e0 = (c & 7) * 8;
            bf16x8 kt;
            kt[0] = f2bf(kxr[g].x); kt[1] = f2bf(kxr[g].y);
            kt[2] = f2bf(kxr[g].z); kt[3] = f2bf(kxr[g].w);
            kt[4] = f2bf(kyr[g].x); kt[5] = f2bf(kyr[g].y);
            kt[6] = f2bf(kyr[g].z); kt[7] = f2bf(kyr[g].w);
            *(bf16x8*)((char*)Kl + swz(s, e0 * 2)) = kt;
            float vv[8] = {vxr[g].x, vxr[g].y, vxr[g].z, vxr[g].w,
                           vyr[g].x, vyr[g].y, vyr[g].z, vyr[g].w};
            #pragma unroll
            for (int jj = 0; jj < 8; ++jj)
                *(short*)((char*)Vl + swzV(e0 + jj, s * 2)) = f2bf(vv[jj]);
        }
    };

    // ---- online-softmax state (log2-scaled domain) ----
    float m[4], lsum[4];
    f32x4 oacc[4];
    #pragma unroll
    for (int r = 0; r < 4; ++r) { m[r] = -INFINITY; lsum[r] = 0.0f; }
    #pragma unroll
    for (int dt = 0; dt < 4; ++dt) oacc[dt] = (f32x4){0.f, 0.f, 0.f, 0.f};

    const int nkv = iq + 1;
    issue_loads(0);
    for (int t = 0; t < nkv; ++t) {
        const int sbase = t * KVBLK;
        __syncthreads();   // previous iteration's LDS reads complete
        write_lds();
        if (t + 1 < nkv) issue_loads(t + 1);   // latency hides under compute
        __syncthreads();

        // ---- S = Q K^T (log2-scaled): 4 col-tiles x (K=64 -> 2 MFMA) ----
        f32x4 sacc[4];
        #pragma unroll
        for (int ct = 0; ct < 4; ++ct) sacc[ct] = (f32x4){0.f, 0.f, 0.f, 0.f};
        #pragma unroll
        for (int ct = 0; ct < 4; ++ct) {
            const int srow = ct * 16 + l16;
            #pragma unroll
            for (int kf = 0; kf < 2; ++kf) {
                bf16x8 bf = *(const bf16x8*)((char*)Kl + swz(srow, (lhi * 8 + kf * 32) * 2));
                sacc[ct] = __builtin_amdgcn_mfma_f32_16x16x32_bf16(qf[kf], bf, sacc[ct], 0, 0, 0);
            }
        }

        // ---- causal mask (diagonal tile only) ----
        if (t == nkv - 1) {
            #pragma unroll
            for (int ct = 0; ct < 4; ++ct) {
                const int sg = sbase + ct * 16 + l16;
                #pragma unroll
                for (int r = 0; r < 4; ++r) {
                    const int qg = qbase + w * 16 + lhi * 4 + r;
                    if (sg > qg) sacc[ct][r] = -INFINITY;
                }
            }
        }

        // ---- online softmax ----
        float corr[4];
        #pragma unroll
        for (int r = 0; r < 4; ++r) {
            float v = fmaxf(fmaxf(sacc[0][r], sacc[1][r]),
                            fmaxf(sacc[2][r], sacc[3][r]));
            v = fmaxf(v, __shfl_xor(v, 1));
            v = fmaxf(v, __shfl_xor(v, 2));
            v = fmaxf(v, __shfl_xor(v, 4));
            v = fmaxf(v, __shfl_xor(v, 8));
            const float mn = fmaxf(m[r], v);
            corr[r] = exp2f(m[r] - mn);
            m[r] = mn;
        }
        float rs[4] = {0.f, 0.f, 0.f, 0.f};
        #pragma unroll
        for (int ct = 0; ct < 4; ++ct) {
            #pragma unroll
            for (int r = 0; r < 4; ++r) {
                const float p = exp2f(sacc[ct][r] - m[r]);
                sacc[ct][r] = p;
                rs[r] += p;
            }
        }
        #pragma unroll
        for (int r = 0; r < 4; ++r) {
            float v = rs[r];
            v += __shfl_xor(v, 1);
            v += __shfl_xor(v, 2);
            v += __shfl_xor(v, 4);
            v += __shfl_xor(v, 8);
            lsum[r] = lsum[r] * corr[r] + v;
        }
        #pragma unroll
        for (int dt = 0; dt < 4; ++dt)
            #pragma unroll
            for (int r = 0; r < 4; ++r) oacc[dt][r] *= corr[r];

        // ---- P: C-layout -> A-layout via per-wave LDS round trip ----
        char* pw = (char*)Pl[w];
        #pragma unroll
        for (int ct = 0; ct < 4; ++ct)
            #pragma unroll
            for (int r = 0; r < 4; ++r)
                *(short*)(pw + swz(lhi * 4 + r, (ct * 16 + l16) * 2)) = f2bf(sacc[ct][r]);
        asm volatile("s_waitcnt lgkmcnt(0)" ::: "memory");
        bf16x8 pa[2];
        #pragma unroll
        for (int kf = 0; kf < 2; ++kf)
            pa[kf] = *(const bf16x8*)(pw + swz(l16, (lhi * 8 + kf * 32) * 2));

        // ---- O += P V : B-operand from transposed V_lds ----
        #pragma unroll
        for (int dt = 0; dt < 4; ++dt) {
            const int vrow = dt * 16 + l16;   // d index
            #pragma unroll
            for (int kf = 0; kf < 2; ++kf) {
                bf16x8 bf = *(const bf16x8*)((char*)Vl + swzV(vrow, (lhi * 8 + kf * 32) * 2));
                oacc[dt] = __builtin_amdgcn_mfma_f32_16x16x32_bf16(pa[kf], bf, oacc[dt], 0, 0, 0);
            }
        }
    }

    // ---- epilogue: normalize and store fp32 ----
    float inv[4];
    #pragma unroll
    for (int r = 0; r < 4; ++r) inv[r] = 1.0f / lsum[r];
    #pragma unroll
    for (int dt = 0; dt < 4; ++dt) {
        #pragma unroll
        for (int r = 0; r < 4; ++r) {
            const int qg = qbase + w * 16 + lhi * 4 + r;
            O[bhoff + (size_t)qg * rowstride + dt * 16 + l16] = oacc[dt][r] * inv[r];
        }
    }
}

extern "C" void kernel_launch(void* const* d_in, const int* in_sizes, int n_in,
                              void* d_out, int out_size, void* d_ws, size_t ws_size,
                              hipStream_t stream) {
    const float* Q = (const float*)d_in[0];
    const float* K = (const float*)d_in[1];
    const float* V = (const float*)d_in[2];
    float* O = (float*)d_out;
    const int B = 2;
    dim3 grid((L / QBLK) * B * H);   // 1024 blocks
    dim3 block(256);
    fattn_kernel<<<grid, block, 0, stream>>>(Q, K, V, O);
}

// Round 3
// 61.551 us; speedup vs baseline: 3.3159x; 1.4261x over previous
//
#include <hip/hip_runtime.h>

// Causal flash-attention fwd, B=2 L=2048 H=16 E=D=64, fp32 in/out.
// R3: swapped QK^T (lane-local softmax rows), O^T PV, uniform 33-iter
//     paired q-tile blocks, double-buffered K/V (1 barrier/iter), cvt_pk
//     bf16 conversion, b64-packed V transpose staging.

using f32x4  = __attribute__((ext_vector_type(4))) float;
using bf16x8 = __attribute__((ext_vector_type(8))) short;
using u32x2  = __attribute__((ext_vector_type(2))) unsigned int;
using u32x4  = __attribute__((ext_vector_type(4))) unsigned int;

constexpr int L = 2048;
constexpr int H = 16;
constexpr int E = 64;
constexpr int QBLK = 64;
constexpr int KVBLK = 64;
constexpr float QSC = 0.125f * 1.44269504088896f;  // scale * log2(e)

__device__ __forceinline__ unsigned cvt_pk(float lo, float hi) {
    unsigned r;
    asm("v_cvt_pk_bf16_f32 %0, %1, %2" : "=v"(r) : "v"(lo), "v"(hi));
    return r;
}
// XOR-swizzle for 128B rows (K, P): permute 16B chunks by row&7
__device__ __forceinline__ int swz(int row, int bcol) {
    return (row * 128 + bcol) ^ ((row & 7) << 4);
}
// V^T rows: mix row>>3 too so the b64 column-pack writes spread banks
__device__ __forceinline__ int swzV(int row, int bcol) {
    return (row * 128 + bcol) ^ ((((row & 7) ^ (row >> 3)) & 7) << 4);
}

__global__ __launch_bounds__(256)
void fattn_kernel(const float* __restrict__ Q,
                  const float* __restrict__ K,
                  const float* __restrict__ V,
                  float* __restrict__ O)
{
    __shared__ short Kl[2][KVBLK * 64];   // [s][e], swizzled
    __shared__ short Vl[2][64 * KVBLK];   // [d][s], swizzled (V^T)
    __shared__ short Pl[4][16 * 64];      // per-wave [q][k], swizzled

    const int bx  = blockIdx.x;
    const int xcd = bx & 7;
    const int j   = bx >> 3;            // 0..63
    const int bh  = (j & 3) * 8 + xcd;  // all 16 pair-blocks of a bh on one XCD
    const int pa  = j >> 2;             // 0..15
    const int h   = bh & 15;
    const int b   = bh >> 4;
    const int tid = threadIdx.x;
    const int w    = tid >> 6;
    const int lane = tid & 63;
    const int l16  = lane & 15;
    const int lhi  = lane >> 4;

    const size_t bhoff = (size_t)b * L * (H * E) + (size_t)h * E;
    const int rs_ = H * E;  // 1024 floats between consecutive seq positions

    // V staging: thread covers 4 s x 4 d
    const int sv0 = (tid >> 4) * 4;
    const int d0  = (tid & 15) * 4;

    f32x4 ka[2][2];   // K prefetch: 2 chunks x 8 floats
    f32x4 va[4];      // V prefetch: rows sv0..sv0+3, cols d0..d0+3

    auto issue_loads = [&](int t) {
        const int sb = t * KVBLK;
        #pragma unroll
        for (int g = 0; g < 2; ++g) {
            const int c = g * 256 + tid;
            const int s = c >> 3;
            const int e0 = (c & 7) * 8;
            const f32x4* kp = (const f32x4*)(K + bhoff + (size_t)(sb + s) * rs_ + e0);
            ka[g][0] = kp[0];
            ka[g][1] = kp[1];
        }
        #pragma unroll
        for (int jj = 0; jj < 4; ++jj)
            va[jj] = *(const f32x4*)(V + bhoff + (size_t)(sb + sv0 + jj) * rs_ + d0);
    };
    auto write_lds = [&](int bufi) {
        short* Kb = Kl[bufi];
        short* Vb = Vl[bufi];
        #pragma unroll
        for (int g = 0; g < 2; ++g) {
            const int c = g * 256 + tid;
            const int s = c >> 3;
            const int e0 = (c & 7) * 8;
            u32x4 kt;
            kt[0] = cvt_pk(ka[g][0][0], ka[g][0][1]);
            kt[1] = cvt_pk(ka[g][0][2], ka[g][0][3]);
            kt[2] = cvt_pk(ka[g][1][0], ka[g][1][1]);
            kt[3] = cvt_pk(ka[g][1][2], ka[g][1][3]);
            *(u32x4*)((char*)Kb + swz(s, e0 * 2)) = kt;
        }
        #pragma unroll
        for (int dd = 0; dd < 4; ++dd) {   // transpose-pack: 4 bf16 along s
            u32x2 vt;
            vt[0] = cvt_pk(va[0][dd], va[1][dd]);
            vt[1] = cvt_pk(va[2][dd], va[3][dd]);
            *(u32x2*)((char*)Vb + swzV(d0 + dd, sv0 * 2)) = vt;
        }
    };

    // uniform pairing: long tile (31-pa) then short tile (pa) -> 33 iters
    const int iq0 = 31 - pa, iq1 = pa;
    const int total0 = iq0 + 1;
    const int total  = total0 + iq1 + 1;
    auto seq_t = [&](int i) { return i < total0 ? i : i - total0; };

    issue_loads(0);
    write_lds(0);
    issue_loads(seq_t(1));
    __syncthreads();

    bf16x8 qf[2];
    float m_run = -INFINITY, lsum = 0.0f;
    f32x4 oacc[4];
    int qbase = 0, iq = 0, qg = 0;

    for (int i = 0; i < total; ++i) {
        const int ts = seq_t(i);
        if (i == 0 || i == total0) {   // segment init
            iq = (i == 0) ? iq0 : iq1;
            qbase = iq * QBLK;
            qg = qbase + w * 16 + l16;
            const float* qp = Q + bhoff + (size_t)qg * rs_ + lhi * 8;
            #pragma unroll
            for (int kf = 0; kf < 2; ++kf) {
                f32x4 x = *(const f32x4*)(qp + kf * 32);
                f32x4 y = *(const f32x4*)(qp + kf * 32 + 4);
                union { u32x4 u; bf16x8 hh; } r;
                r.u[0] = cvt_pk(x[0] * QSC, x[1] * QSC);
                r.u[1] = cvt_pk(x[2] * QSC, x[3] * QSC);
                r.u[2] = cvt_pk(y[0] * QSC, y[1] * QSC);
                r.u[3] = cvt_pk(y[2] * QSC, y[3] * QSC);
                qf[kf] = r.hh;
            }
            m_run = -INFINITY; lsum = 0.0f;
            #pragma unroll
            for (int dt = 0; dt < 4; ++dt) oacc[dt] = (f32x4){0.f, 0.f, 0.f, 0.f};
        }

        const char* Kb = (const char*)Kl[i & 1];
        const char* Vb = (const char*)Vl[i & 1];

        // S^T = K Q^T : lane gets q = l16, k = st*16 + lhi*4 + r
        f32x4 p[4];
        #pragma unroll
        for (int st = 0; st < 4; ++st) p[st] = (f32x4){0.f, 0.f, 0.f, 0.f};
        #pragma unroll
        for (int st = 0; st < 4; ++st) {
            #pragma unroll
            for (int kf = 0; kf < 2; ++kf) {
                bf16x8 af = *(const bf16x8*)(Kb + swz(st * 16 + l16, (lhi * 8 + kf * 32) * 2));
                p[st] = __builtin_amdgcn_mfma_f32_16x16x32_bf16(af, qf[kf], p[st], 0, 0, 0);
            }
        }

        if (ts == iq) {   // diagonal tile: causal mask (q fixed per lane)
            #pragma unroll
            for (int st = 0; st < 4; ++st)
                #pragma unroll
                for (int r = 0; r < 4; ++r) {
                    const int kg = ts * KVBLK + st * 16 + lhi * 4 + r;
                    if (kg > qg) p[st][r] = -INFINITY;
                }
        }

        // lane-local softmax: 16 values + 2 shuffles across lhi groups
        float mx = -INFINITY;
        #pragma unroll
        for (int st = 0; st < 4; ++st)
            #pragma unroll
            for (int r = 0; r < 4; ++r) mx = fmaxf(mx, p[st][r]);
        mx = fmaxf(mx, __shfl_xor(mx, 16));
        mx = fmaxf(mx, __shfl_xor(mx, 32));
        const float mn = fmaxf(m_run, mx);
        const float corr = exp2f(m_run - mn);
        m_run = mn;
        float rs = 0.f;
        #pragma unroll
        for (int st = 0; st < 4; ++st)
            #pragma unroll
            for (int r = 0; r < 4; ++r) {
                const float e = exp2f(p[st][r] - mn);
                p[st][r] = e;
                rs += e;
            }
        rs += __shfl_xor(rs, 16);
        rs += __shfl_xor(rs, 32);
        lsum = lsum * corr + rs;
        #pragma unroll
        for (int dt = 0; dt < 4; ++dt)
            #pragma unroll
            for (int r = 0; r < 4; ++r) oacc[dt][r] *= corr;

        // P -> LDS (4x b64) -> read back as B-frag of P^T (2x b128)
        char* pw = (char*)Pl[w];
        #pragma unroll
        for (int st = 0; st < 4; ++st) {
            u32x2 pk2;
            pk2[0] = cvt_pk(p[st][0], p[st][1]);
            pk2[1] = cvt_pk(p[st][2], p[st][3]);
            *(u32x2*)(pw + swz(l16, (st * 16 + lhi * 4) * 2)) = pk2;
        }
        asm volatile("s_waitcnt lgkmcnt(0)" ::: "memory");
        __builtin_amdgcn_sched_barrier(0);
        bf16x8 pb[2];
        #pragma unroll
        for (int kf = 0; kf < 2; ++kf)
            pb[kf] = *(const bf16x8*)(pw + swz(l16, (lhi * 8 + kf * 32) * 2));

        // O^T += V^T P^T : lane output q = l16 (matches softmax state)
        #pragma unroll
        for (int dt = 0; dt < 4; ++dt) {
            #pragma unroll
            for (int kf = 0; kf < 2; ++kf) {
                bf16x8 vf = *(const bf16x8*)(Vb + swzV(dt * 16 + l16, (lhi * 8 + kf * 32) * 2));
                oacc[dt] = __builtin_amdgcn_mfma_f32_16x16x32_bf16(vf, pb[kf], oacc[dt], 0, 0, 0);
            }
        }

        // pipeline: stage tile i+1 into alt buffer, issue loads for i+2
        if (i + 1 < total) write_lds((i + 1) & 1);
        if (i + 2 < total) issue_loads(seq_t(i + 2));

        if (ts == iq) {   // segment epilogue: normalize, coalesced f32x4 store
            const float inv = 1.0f / lsum;
            float* op = O + bhoff + (size_t)qg * rs_;
            #pragma unroll
            for (int dt = 0; dt < 4; ++dt) {
                f32x4 o = oacc[dt];
                o[0] *= inv; o[1] *= inv; o[2] *= inv; o[3] *= inv;
                *(f32x4*)(op + dt * 16 + lhi * 4) = o;
            }
        }
        __syncthreads();   // buf[(i+1)&1] staged, buf[i&1] reads done
    }
}

extern "C" void kernel_launch(void* const* d_in, const int* in_sizes, int n_in,
                              void* d_out, int out_size, void* d_ws, size_t ws_size,
                              hipStream_t stream) {
    const float* Q = (const float*)d_in[0];
    const float* K = (const float*)d_in[1];
    const float* V = (const float*)d_in[2];
    float* O = (float*)d_out;
    dim3 grid(512);    // 16 q-tile pairs x 32 (b,h); uniform 33 KV-iters each
    dim3 block(256);
    fattn_kernel<<<grid, block, 0, stream>>>(Q, K, V, O);
}

// Round 4
// 57.164 us; speedup vs baseline: 3.5704x; 1.0767x over previous
//
#include <hip/hip_runtime.h>

// Causal flash-attention fwd, B=2 L=2048 H=16 E=D=64, fp32 in/out.
// R4: in-register P transpose via v_permlane{16,32}_swap (no P LDS round
//     trip), permuted PV k-axis with matching V^T staging, 1024 blocks
//     (4/CU, balanced remap), defer-max rescale, permlane reductions,
//     setprio around MFMA clusters.

using f32x4  = __attribute__((ext_vector_type(4))) float;
using bf16x8 = __attribute__((ext_vector_type(8))) short;
using u32x2  = __attribute__((ext_vector_type(2))) unsigned int;
using u32x4  = __attribute__((ext_vector_type(4))) unsigned int;

constexpr int L = 2048;
constexpr int H = 16;
constexpr int E = 64;
constexpr int QBLK = 64;
constexpr int KVBLK = 64;
constexpr float QSC = 0.125f * 1.44269504088896f;  // scale * log2(e)
constexpr float THR = 8.0f;                        // defer-max threshold (log2)

__device__ __forceinline__ unsigned cvt_pk(float lo, float hi) {
    unsigned r;
    asm("v_cvt_pk_bf16_f32 %0, %1, %2" : "=v"(r) : "v"(lo), "v"(hi));
    return r;
}
// X' = [Xg0,Yg0,Xg2,Yg2], Y' = [Xg1,Yg1,Xg3,Yg3]  (16-lane groups)
__device__ __forceinline__ void pl16(unsigned& a, unsigned& b) {
    asm("v_permlane16_swap_b32 %0, %1" : "+v"(a), "+v"(b));
}
// X' = [Xg0,Xg1,Yg0,Yg1], Y' = [Xg2,Xg3,Yg2,Yg3]
__device__ __forceinline__ void pl32(unsigned& a, unsigned& b) {
    asm("v_permlane32_swap_b32 %0, %1" : "+v"(a), "+v"(b));
}
__device__ __forceinline__ unsigned opaque_copy(unsigned a) {
    unsigned b;
    asm("v_mov_b32 %0, %1" : "=v"(b) : "v"(a));
    return b;
}
// reduce across the 4 lhi groups (lanes l16, +16, +32, +48)
__device__ __forceinline__ float gmax4(float x) {
    unsigned a = __float_as_uint(x), b = opaque_copy(a);
    pl16(a, b);
    float m = fmaxf(__uint_as_float(a), __uint_as_float(b));
    unsigned c = __float_as_uint(m), d = opaque_copy(c);
    pl32(c, d);
    return fmaxf(__uint_as_float(c), __uint_as_float(d));
}
__device__ __forceinline__ float gsum4(float x) {
    unsigned a = __float_as_uint(x), b = opaque_copy(a);
    pl16(a, b);
    float s = __uint_as_float(a) + __uint_as_float(b);
    unsigned c = __float_as_uint(s), d = opaque_copy(c);
    pl32(c, d);
    return __uint_as_float(c) + __uint_as_float(d);
}
// XOR-swizzle for 128B rows (K tile)
__device__ __forceinline__ int swz(int row, int bcol) {
    return (row * 128 + bcol) ^ ((row & 7) << 4);
}
// V^T rows: mix row>>3 so the b64 column-pack writes spread banks
__device__ __forceinline__ int swzV(int row, int bcol) {
    return (row * 128 + bcol) ^ ((((row & 7) ^ (row >> 3)) & 7) << 4);
}

__global__ __launch_bounds__(256, 4)
void fattn_kernel(const float* __restrict__ Q,
                  const float* __restrict__ K,
                  const float* __restrict__ V,
                  float* __restrict__ O)
{
    __shared__ short Kl[2][KVBLK * 64];   // [s][e], swizzled
    __shared__ short Vl[2][64 * KVBLK];   // [d][kcol], swizzled, k = pi(s)

    // ---- balanced XCD-aware remap: 4 same-head blocks per CU, iters sum 66
    const int bx  = blockIdx.x;
    const int xcd = bx & 7;
    const int j   = bx >> 3;             // 0..127 within XCD
    const int bh  = (j & 3) * 8 + xcd;   // 4 heads per XCD
    const int v_  = j >> 2;              // 0..31
    const int q2  = v_ >> 3, x_ = v_ & 7;
    const int iq  = (q2 & 1) ? (31 - (q2 >> 1) - 2 * x_) : (2 * x_ + (q2 >> 1));
    const int h   = bh & 15;
    const int b   = bh >> 4;
    const int tid = threadIdx.x;
    const int w    = tid >> 6;
    const int lane = tid & 63;
    const int l16  = lane & 15;
    const int lhi  = lane >> 4;

    const size_t bhoff = (size_t)b * L * (H * E) + (size_t)h * E;
    const int rs_ = H * E;               // 1024 floats between seq positions

    // V staging: thread covers 4 s x 4 d; k-column = pi(s): s=16a+8b2+c -> 32b2+8a+c
    const int sv0 = (tid >> 4) * 4;
    const int d0  = (tid & 15) * 4;
    const int kc  = ((sv0 >> 3) & 1) * 32 + (sv0 >> 4) * 8 + (sv0 & 7);

    f32x4 ka[2][2];
    f32x4 va[4];

    auto issue_loads = [&](int t) {
        const int sb = t * KVBLK;
        #pragma unroll
        for (int g = 0; g < 2; ++g) {
            const int c = g * 256 + tid;
            const int s = c >> 3;
            const int e0 = (c & 7) * 8;
            const f32x4* kp = (const f32x4*)(K + bhoff + (size_t)(sb + s) * rs_ + e0);
            ka[g][0] = kp[0];
            ka[g][1] = kp[1];
        }
        #pragma unroll
        for (int jj = 0; jj < 4; ++jj)
            va[jj] = *(const f32x4*)(V + bhoff + (size_t)(sb + sv0 + jj) * rs_ + d0);
    };
    auto write_lds = [&](int bufi) {
        short* Kb = Kl[bufi];
        short* Vb = Vl[bufi];
        #pragma unroll
        for (int g = 0; g < 2; ++g) {
            const int c = g * 256 + tid;
            const int s = c >> 3;
            const int e0 = (c & 7) * 8;
            u32x4 kt;
            kt[0] = cvt_pk(ka[g][0][0], ka[g][0][1]);
            kt[1] = cvt_pk(ka[g][0][2], ka[g][0][3]);
            kt[2] = cvt_pk(ka[g][1][0], ka[g][1][1]);
            kt[3] = cvt_pk(ka[g][1][2], ka[g][1][3]);
            *(u32x4*)((char*)Kb + swz(s, e0 * 2)) = kt;
        }
        #pragma unroll
        for (int dd = 0; dd < 4; ++dd) {
            u32x2 vt;
            vt[0] = cvt_pk(va[0][dd], va[1][dd]);
            vt[1] = cvt_pk(va[2][dd], va[3][dd]);
            *(u32x2*)((char*)Vb + swzV(d0 + dd, kc * 2)) = vt;
        }
    };

    // ---- Q fragment (B-operand of swapped QK^T), scale*log2e folded ----
    const int qg = iq * QBLK + w * 16 + l16;
    bf16x8 qf[2];
    {
        const float* qp = Q + bhoff + (size_t)qg * rs_ + lhi * 8;
        #pragma unroll
        for (int kf = 0; kf < 2; ++kf) {
            f32x4 xv = *(const f32x4*)(qp + kf * 32);
            f32x4 yv = *(const f32x4*)(qp + kf * 32 + 4);
            union { u32x4 u; bf16x8 hh; } r;
            r.u[0] = cvt_pk(xv[0] * QSC, xv[1] * QSC);
            r.u[1] = cvt_pk(xv[2] * QSC, xv[3] * QSC);
            r.u[2] = cvt_pk(yv[0] * QSC, yv[1] * QSC);
            r.u[3] = cvt_pk(yv[2] * QSC, yv[3] * QSC);
            qf[kf] = r.hh;
        }
    }

    float m_run = -INFINITY, lsum = 0.0f;
    f32x4 oacc[4];
    #pragma unroll
    for (int dt = 0; dt < 4; ++dt) oacc[dt] = (f32x4){0.f, 0.f, 0.f, 0.f};

    const int total = iq + 1;
    issue_loads(0);
    write_lds(0);
    if (total > 1) issue_loads(1);
    __syncthreads();

    for (int i = 0; i < total; ++i) {
        const char* Kb = (const char*)Kl[i & 1];
        const char* Vb = (const char*)Vl[i & 1];

        // ---- S^T = K Q^T: lane owns q = l16; p[st][r] is s = st*16+lhi*4+r
        f32x4 p[4];
        #pragma unroll
        for (int st = 0; st < 4; ++st) p[st] = (f32x4){0.f, 0.f, 0.f, 0.f};
        __builtin_amdgcn_s_setprio(1);
        #pragma unroll
        for (int st = 0; st < 4; ++st) {
            #pragma unroll
            for (int kf = 0; kf < 2; ++kf) {
                bf16x8 af = *(const bf16x8*)(Kb + swz(st * 16 + l16, (lhi * 8 + kf * 32) * 2));
                p[st] = __builtin_amdgcn_mfma_f32_16x16x32_bf16(af, qf[kf], p[st], 0, 0, 0);
            }
        }
        __builtin_amdgcn_s_setprio(0);

        if (i == total - 1) {   // diagonal tile: causal mask
            #pragma unroll
            for (int st = 0; st < 4; ++st)
                #pragma unroll
                for (int r = 0; r < 4; ++r) {
                    const int kg = i * KVBLK + st * 16 + lhi * 4 + r;
                    if (kg > qg) p[st][r] = -INFINITY;
                }
        }

        // ---- stage next tile (other buffer), then prefetch tile i+2 ----
        if (i + 1 < total) write_lds((i + 1) & 1);
        if (i + 2 < total) issue_loads(i + 2);

        // ---- online softmax (lane-local row, defer-max) ----
        float mx = -INFINITY;
        #pragma unroll
        for (int st = 0; st < 4; ++st)
            #pragma unroll
            for (int r = 0; r < 4; ++r) mx = fmaxf(mx, p[st][r]);
        mx = gmax4(mx);
        if (!__all(mx <= m_run + THR)) {
            const float mn = fmaxf(m_run, mx);
            const float corr = exp2f(m_run - mn);
            lsum *= corr;
            #pragma unroll
            for (int dt = 0; dt < 4; ++dt)
                #pragma unroll
                for (int r = 0; r < 4; ++r) oacc[dt][r] *= corr;
            m_run = mn;
        }
        float rsum = 0.f;
        #pragma unroll
        for (int st = 0; st < 4; ++st)
            #pragma unroll
            for (int r = 0; r < 4; ++r) {
                const float e = exp2f(p[st][r] - m_run);
                p[st][r] = e;
                rsum += e;
            }
        lsum += gsum4(rsum);

        // ---- P -> bf16 pack + in-register 4-group transpose ----
        // wp[st][h] = bf16x2(s = st*16 + lhi*4 + 2h, +1)
        unsigned wp[4][2];
        #pragma unroll
        for (int st = 0; st < 4; ++st) {
            wp[st][0] = cvt_pk(p[st][0], p[st][1]);
            wp[st][1] = cvt_pk(p[st][2], p[st][3]);
        }
        #pragma unroll
        for (int hh = 0; hh < 2; ++hh) {
            pl16(wp[0][hh], wp[1][hh]);
            pl16(wp[2][hh], wp[3][hh]);
            pl32(wp[0][hh], wp[2][hh]);
            pl32(wp[1][hh], wp[3][hh]);
        }
        // after transpose, lane group g holds s{16g+off}: pb B-frag with
        // k = pi(s); pb[kf] word j = s{16*lhi + 8*kf + 2j, +1}
        union { u32x4 u; bf16x8 v; } pb0, pb1;
        pb0.u[0] = wp[0][0]; pb0.u[1] = wp[0][1];
        pb0.u[2] = wp[1][0]; pb0.u[3] = wp[1][1];
        pb1.u[0] = wp[2][0]; pb1.u[1] = wp[2][1];
        pb1.u[2] = wp[3][0]; pb1.u[3] = wp[3][1];

        // ---- O^T += V^T P^T (k-axis permuted consistently on both sides)
        __builtin_amdgcn_s_setprio(1);
        #pragma unroll
        for (int dt = 0; dt < 4; ++dt) {
            bf16x8 vf0 = *(const bf16x8*)(Vb + swzV(dt * 16 + l16, (lhi * 8) * 2));
            oacc[dt] = __builtin_amdgcn_mfma_f32_16x16x32_bf16(vf0, pb0.v, oacc[dt], 0, 0, 0);
            bf16x8 vf1 = *(const bf16x8*)(Vb + swzV(dt * 16 + l16, (lhi * 8 + 32) * 2));
            oacc[dt] = __builtin_amdgcn_mfma_f32_16x16x32_bf16(vf1, pb1.v, oacc[dt], 0, 0, 0);
        }
        __builtin_amdgcn_s_setprio(0);

        if (i + 1 < total) __syncthreads();
    }

    // ---- epilogue: normalize, coalesced f32x4 store ----
    const float inv = 1.0f / lsum;
    float* op = O + bhoff + (size_t)qg * rs_;
    #pragma unroll
    for (int dt = 0; dt < 4; ++dt) {
        f32x4 o = oacc[dt];
        o[0] *= inv; o[1] *= inv; o[2] *= inv; o[3] *= inv;
        *(f32x4*)(op + dt * 16 + lhi * 4) = o;
    }
}

extern "C" void kernel_launch(void* const* d_in, const int* in_sizes, int n_in,
                              void* d_out, int out_size, void* d_ws, size_t ws_size,
                              hipStream_t stream) {
    const float* Q = (const float*)d_in[0];
    const float* K = (const float*)d_in[1];
    const float* V = (const float*)d_in[2];
    float* O = (float*)d_out;
    dim3 grid(1024);   // 32 (b,h) x 32 q-tiles; 4 blocks/CU, balanced remap
    dim3 block(256);
    fattn_kernel<<<grid, block, 0, stream>>>(Q, K, V, O);
}

// Round 5
// 50.470 us; speedup vs baseline: 4.0440x; 1.1326x over previous
//
#include <hip/hip_runtime.h>

// Causal flash-attention fwd, B=2 L=2048 H=16 E=D=64, fp32 in/out.
// R5: native v_exp_f32 (builtin exp2), bf16 pre-pass (pre-swizzled K tiles,
//     transposed+permuted+pre-swizzled V tiles in d_ws) -> main-loop staging
//     is pure b128 copy; balanced reduction trees. R4 kernel kept as
//     fallback if ws_size < 16MB.

using f32x4  = __attribute__((ext_vector_type(4))) float;
using bf16x8 = __attribute__((ext_vector_type(8))) short;
using u32x2  = __attribute__((ext_vector_type(2))) unsigned int;
using u32x4  = __attribute__((ext_vector_type(4))) unsigned int;

constexpr int L = 2048;
constexpr int H = 16;
constexpr int E = 64;
constexpr int QBLK = 64;
constexpr int KVBLK = 64;
constexpr float QSC = 0.125f * 1.44269504088896f;  // scale * log2(e)
constexpr float THR = 8.0f;                        // defer-max threshold

#if defined(__has_builtin)
#if __has_builtin(__builtin_amdgcn_exp2f)
#define HAVE_EXP2 1
#endif
#endif
__device__ __forceinline__ float fexp2(float x) {
#ifdef HAVE_EXP2
    return __builtin_amdgcn_exp2f(x);
#else
    float r;
    asm("v_exp_f32 %0, %1" : "=v"(r) : "v"(x));
    return r;
#endif
}

__device__ __forceinline__ unsigned cvt_pk(float lo, float hi) {
    unsigned r;
    asm("v_cvt_pk_bf16_f32 %0, %1, %2" : "=v"(r) : "v"(lo), "v"(hi));
    return r;
}
__device__ __forceinline__ void pl16(unsigned& a, unsigned& b) {
    asm("v_permlane16_swap_b32 %0, %1" : "+v"(a), "+v"(b));
}
__device__ __forceinline__ void pl32(unsigned& a, unsigned& b) {
    asm("v_permlane32_swap_b32 %0, %1" : "+v"(a), "+v"(b));
}
__device__ __forceinline__ unsigned opaque_copy(unsigned a) {
    unsigned b;
    asm("v_mov_b32 %0, %1" : "=v"(b) : "v"(a));
    return b;
}
__device__ __forceinline__ float gmax4(float x) {
    unsigned a = __float_as_uint(x), b = opaque_copy(a);
    pl16(a, b);
    float m = fmaxf(__uint_as_float(a), __uint_as_float(b));
    unsigned c = __float_as_uint(m), d = opaque_copy(c);
    pl32(c, d);
    return fmaxf(__uint_as_float(c), __uint_as_float(d));
}
__device__ __forceinline__ float gsum4(float x) {
    unsigned a = __float_as_uint(x), b = opaque_copy(a);
    pl16(a, b);
    float s = __uint_as_float(a) + __uint_as_float(b);
    unsigned c = __float_as_uint(s), d = opaque_copy(c);
    pl32(c, d);
    return __uint_as_float(c) + __uint_as_float(d);
}
// XOR-swizzle for 128B rows (K tile)
__device__ __forceinline__ int swz(int row, int bcol) {
    return (row * 128 + bcol) ^ ((row & 7) << 4);
}
// V^T rows: mix row>>3 too
__device__ __forceinline__ int swzV(int row, int bcol) {
    return (row * 128 + bcol) ^ ((((row & 7) ^ (row >> 3)) & 7) << 4);
}

// ---------------- pre-pass: f32 K,V -> bf16 swizzled tiles in ws ----------
// Kb tile (bh,t), 4096 shorts: short-off r*64 + ((j^ (r&7))*8) holds
//   K[t*64+r][8*(j^(r&7))... ] i.e. chunk j' holds cols 8*(j'^(r&7)).
// Vb tile: short-off d*64 + j'*8 holds V^T[d][cols 8*(j'^F(d)) + i] where
//   col = 32*b2 + 8*a + c maps to s = 16*a + 8*b2 + c  (PV k-permutation).
__global__ __launch_bounds__(256)
void prep_kernel(const float* __restrict__ K, const float* __restrict__ V,
                 short* __restrict__ Kb, short* __restrict__ Vb)
{
    __shared__ float Vt[64][65];
    const int bx  = blockIdx.x;
    const int t   = bx & 31;
    const int bh  = bx >> 5;
    const int tid = threadIdx.x;
    const size_t bhoff = (size_t)(bh >> 4) * L * (H * E) + (size_t)(bh & 15) * E;
    const size_t tileo = (size_t)(bh * 32 + t) * 4096;

    #pragma unroll
    for (int g = 0; g < 2; ++g) {
        const int c  = g * 256 + tid;
        const int r  = c >> 3;
        const int e0 = (c & 7) * 8;
        const float* kp = K + bhoff + (size_t)(t * 64 + r) * 1024 + e0;
        f32x4 k0 = *(const f32x4*)kp, k1 = *(const f32x4*)(kp + 4);
        u32x4 kt;
        kt[0] = cvt_pk(k0[0], k0[1]); kt[1] = cvt_pk(k0[2], k0[3]);
        kt[2] = cvt_pk(k1[0], k1[1]); kt[3] = cvt_pk(k1[2], k1[3]);
        *(u32x4*)(Kb + tileo + r * 64 + (((e0 >> 3) ^ (r & 7)) * 8)) = kt;
        const float* vp = V + bhoff + (size_t)(t * 64 + r) * 1024 + e0;
        f32x4 v0 = *(const f32x4*)vp, v1 = *(const f32x4*)(vp + 4);
        #pragma unroll
        for (int k2 = 0; k2 < 4; ++k2) { Vt[r][e0 + k2] = v0[k2]; Vt[r][e0 + 4 + k2] = v1[k2]; }
    }
    __syncthreads();
    #pragma unroll
    for (int g = 0; g < 2; ++g) {
        const int c  = g * 256 + tid;
        const int d  = c >> 3;
        const int jp = c & 7;
        const int F  = ((d & 7) ^ (d >> 3)) & 7;
        const int col0 = 8 * (jp ^ F);
        float vals[8];
        #pragma unroll
        for (int i = 0; i < 8; ++i) {
            const int col = col0 + i;
            const int s = 16 * ((col >> 3) & 3) + 8 * (col >> 5) + (col & 7);
            vals[i] = Vt[s][d];
        }
        u32x4 vt;
        vt[0] = cvt_pk(vals[0], vals[1]); vt[1] = cvt_pk(vals[2], vals[3]);
        vt[2] = cvt_pk(vals[4], vals[5]); vt[3] = cvt_pk(vals[6], vals[7]);
        *(u32x4*)(Vb + tileo + d * 64 + jp * 8) = vt;
    }
}

// ---------------- main kernel: staging = pure b128 copy ----------------
__global__ __launch_bounds__(256, 4)
void fattn_main(const float* __restrict__ Q,
                const short* __restrict__ Kb,
                const short* __restrict__ Vb,
                float* __restrict__ O)
{
    __shared__ short Kl[2][4096];
    __shared__ short Vl[2][4096];

    const int bx  = blockIdx.x;
    const int xcd = bx & 7;
    const int j   = bx >> 3;
    const int bh  = (j & 3) * 8 + xcd;
    const int v_  = j >> 2;
    const int q2  = v_ >> 3, x_ = v_ & 7;
    const int iq  = (q2 & 1) ? (31 - (q2 >> 1) - 2 * x_) : (2 * x_ + (q2 >> 1));
    const int tid = threadIdx.x;
    const int w    = tid >> 6;
    const int lane = tid & 63;
    const int l16  = lane & 15;
    const int lhi  = lane >> 4;

    const size_t bhoff  = (size_t)(bh >> 4) * L * (H * E) + (size_t)(bh & 15) * E;
    const int rs_ = H * E;
    const size_t kvbase = (size_t)bh * 32 * 4096;   // shorts

    u32x4 kreg[2], vreg[2];
    auto stage_regs = [&](int t) {
        const u32x4* kp = (const u32x4*)(Kb + kvbase + (size_t)t * 4096);
        const u32x4* vp = (const u32x4*)(Vb + kvbase + (size_t)t * 4096);
        #pragma unroll
        for (int g = 0; g < 2; ++g) {
            kreg[g] = kp[g * 256 + tid];
            vreg[g] = vp[g * 256 + tid];
        }
    };
    auto write_stage = [&](int buf) {
        #pragma unroll
        for (int g = 0; g < 2; ++g) {
            ((u32x4*)Kl[buf])[g * 256 + tid] = kreg[g];
            ((u32x4*)Vl[buf])[g * 256 + tid] = vreg[g];
        }
    };

    // Q fragment (B-operand of swapped QK^T), scale*log2e folded
    const int qg = iq * QBLK + w * 16 + l16;
    bf16x8 qf[2];
    {
        const float* qp = Q + bhoff + (size_t)qg * rs_ + lhi * 8;
        #pragma unroll
        for (int kf = 0; kf < 2; ++kf) {
            f32x4 xv = *(const f32x4*)(qp + kf * 32);
            f32x4 yv = *(const f32x4*)(qp + kf * 32 + 4);
            union { u32x4 u; bf16x8 hh; } r;
            r.u[0] = cvt_pk(xv[0] * QSC, xv[1] * QSC);
            r.u[1] = cvt_pk(xv[2] * QSC, xv[3] * QSC);
            r.u[2] = cvt_pk(yv[0] * QSC, yv[1] * QSC);
            r.u[3] = cvt_pk(yv[2] * QSC, yv[3] * QSC);
            qf[kf] = r.hh;
        }
    }

    float m_run = -INFINITY, lsum = 0.0f;
    f32x4 oacc[4];
    #pragma unroll
    for (int dt = 0; dt < 4; ++dt) oacc[dt] = (f32x4){0.f, 0.f, 0.f, 0.f};

    const int total = iq + 1;
    stage_regs(0);
    write_stage(0);
    if (total > 1) stage_regs(1);
    __syncthreads();

    for (int i = 0; i < total; ++i) {
        const char* Kbl = (const char*)Kl[i & 1];
        const char* Vbl = (const char*)Vl[i & 1];

        // S^T = K Q^T : lane owns q = l16; p[st][r] is s = st*16+lhi*4+r
        f32x4 p[4];
        #pragma unroll
        for (int st = 0; st < 4; ++st) p[st] = (f32x4){0.f, 0.f, 0.f, 0.f};
        __builtin_amdgcn_s_setprio(1);
        #pragma unroll
        for (int st = 0; st < 4; ++st) {
            #pragma unroll
            for (int kf = 0; kf < 2; ++kf) {
                bf16x8 af = *(const bf16x8*)(Kbl + swz(st * 16 + l16, (lhi * 8 + kf * 32) * 2));
                p[st] = __builtin_amdgcn_mfma_f32_16x16x32_bf16(af, qf[kf], p[st], 0, 0, 0);
            }
        }
        __builtin_amdgcn_s_setprio(0);

        if (i == total - 1) {   // diagonal tile: causal mask
            #pragma unroll
            for (int st = 0; st < 4; ++st)
                #pragma unroll
                for (int r = 0; r < 4; ++r) {
                    const int kg = i * KVBLK + st * 16 + lhi * 4 + r;
                    if (kg > qg) p[st][r] = -INFINITY;
                }
        }

        // stage next tile into the free buffer; prefetch tile i+2
        if (i + 1 < total) write_stage((i + 1) & 1);
        if (i + 2 < total) stage_regs(i + 2);

        // online softmax (lane-local row, defer-max), balanced trees
        f32x4 mv = p[0];
        #pragma unroll
        for (int st = 1; st < 4; ++st)
            #pragma unroll
            for (int r = 0; r < 4; ++r) mv[r] = fmaxf(mv[r], p[st][r]);
        float mx = fmaxf(fmaxf(mv[0], mv[1]), fmaxf(mv[2], mv[3]));
        mx = gmax4(mx);
        if (!__all(mx <= m_run + THR)) {
            const float mn = fmaxf(m_run, mx);
            const float corr = fexp2(m_run - mn);
            lsum *= corr;
            #pragma unroll
            for (int dt = 0; dt < 4; ++dt)
                #pragma unroll
                for (int r = 0; r < 4; ++r) oacc[dt][r] *= corr;
            m_run = mn;
        }
        f32x4 rsv = (f32x4){0.f, 0.f, 0.f, 0.f};
        #pragma unroll
        for (int st = 0; st < 4; ++st)
            #pragma unroll
            for (int r = 0; r < 4; ++r) {
                const float e = fexp2(p[st][r] - m_run);
                p[st][r] = e;
                rsv[r] += e;
            }
        lsum += gsum4((rsv[0] + rsv[1]) + (rsv[2] + rsv[3]));

        // P -> bf16 pack + in-register 4-group transpose
        unsigned wp[4][2];
        #pragma unroll
        for (int st = 0; st < 4; ++st) {
            wp[st][0] = cvt_pk(p[st][0], p[st][1]);
            wp[st][1] = cvt_pk(p[st][2], p[st][3]);
        }
        #pragma unroll
        for (int hh = 0; hh < 2; ++hh) {
            pl16(wp[0][hh], wp[1][hh]);
            pl16(wp[2][hh], wp[3][hh]);
            pl32(wp[0][hh], wp[2][hh]);
            pl32(wp[1][hh], wp[3][hh]);
        }
        union { u32x4 u; bf16x8 v; } pb0, pb1;
        pb0.u[0] = wp[0][0]; pb0.u[1] = wp[0][1];
        pb0.u[2] = wp[1][0]; pb0.u[3] = wp[1][1];
        pb1.u[0] = wp[2][0]; pb1.u[1] = wp[2][1];
        pb1.u[2] = wp[3][0]; pb1.u[3] = wp[3][1];

        // O^T += V^T P^T (k-axis permuted consistently on both sides)
        __builtin_amdgcn_s_setprio(1);
        #pragma unroll
        for (int dt = 0; dt < 4; ++dt) {
            bf16x8 vf0 = *(const bf16x8*)(Vbl + swzV(dt * 16 + l16, (lhi * 8) * 2));
            oacc[dt] = __builtin_amdgcn_mfma_f32_16x16x32_bf16(vf0, pb0.v, oacc[dt], 0, 0, 0);
            bf16x8 vf1 = *(const bf16x8*)(Vbl + swzV(dt * 16 + l16, (lhi * 8 + 32) * 2));
            oacc[dt] = __builtin_amdgcn_mfma_f32_16x16x32_bf16(vf1, pb1.v, oacc[dt], 0, 0, 0);
        }
        __builtin_amdgcn_s_setprio(0);

        if (i + 1 < total) __syncthreads();
    }

    const float inv = 1.0f / lsum;
    float* op = O + bhoff + (size_t)qg * rs_;
    #pragma unroll
    for (int dt = 0; dt < 4; ++dt) {
        f32x4 o = oacc[dt];
        o[0] *= inv; o[1] *= inv; o[2] *= inv; o[3] *= inv;
        *(f32x4*)(op + dt * 16 + lhi * 4) = o;
    }
}

// ---------------- fallback (R4 structure, f32 K/V staging) ----------------
__global__ __launch_bounds__(256, 4)
void fattn_fb(const float* __restrict__ Q,
              const float* __restrict__ K,
              const float* __restrict__ V,
              float* __restrict__ O)
{
    __shared__ short Kl[2][KVBLK * 64];
    __shared__ short Vl[2][64 * KVBLK];

    const int bx  = blockIdx.x;
    const int xcd = bx & 7;
    const int j   = bx >> 3;
    const int bh  = (j & 3) * 8 + xcd;
    const int v_  = j >> 2;
    const int q2  = v_ >> 3, x_ = v_ & 7;
    const int iq  = (q2 & 1) ? (31 - (q2 >> 1) - 2 * x_) : (2 * x_ + (q2 >> 1));
    const int tid = threadIdx.x;
    const int w    = tid >> 6;
    const int lane = tid & 63;
    const int l16  = lane & 15;
    const int lhi  = lane >> 4;

    const size_t bhoff = (size_t)(bh >> 4) * L * (H * E) + (size_t)(bh & 15) * E;
    const int rs_ = H * E;
    const int sv0 = (tid >> 4) * 4;
    const int d0  = (tid & 15) * 4;
    const int kc  = ((sv0 >> 3) & 1) * 32 + (sv0 >> 4) * 8 + (sv0 & 7);

    f32x4 ka[2][2];
    f32x4 va[4];
    auto issue_loads = [&](int t) {
        const int sb = t * KVBLK;
        #pragma unroll
        for (int g = 0; g < 2; ++g) {
            const int c = g * 256 + tid;
            const int s = c >> 3;
            const int e0 = (c & 7) * 8;
            const f32x4* kp = (const f32x4*)(K + bhoff + (size_t)(sb + s) * rs_ + e0);
            ka[g][0] = kp[0];
            ka[g][1] = kp[1];
        }
        #pragma unroll
        for (int jj = 0; jj < 4; ++jj)
            va[jj] = *(const f32x4*)(V + bhoff + (size_t)(sb + sv0 + jj) * rs_ + d0);
    };
    auto write_lds = [&](int bufi) {
        short* Kb = Kl[bufi];
        short* Vb = Vl[bufi];
        #pragma unroll
        for (int g = 0; g < 2; ++g) {
            const int c = g * 256 + tid;
            const int s = c >> 3;
            const int e0 = (c & 7) * 8;
            u32x4 kt;
            kt[0] = cvt_pk(ka[g][0][0], ka[g][0][1]);
            kt[1] = cvt_pk(ka[g][0][2], ka[g][0][3]);
            kt[2] = cvt_pk(ka[g][1][0], ka[g][1][1]);
            kt[3] = cvt_pk(ka[g][1][2], ka[g][1][3]);
            *(u32x4*)((char*)Kb + swz(s, e0 * 2)) = kt;
        }
        #pragma unroll
        for (int dd = 0; dd < 4; ++dd) {
            u32x2 vt;
            vt[0] = cvt_pk(va[0][dd], va[1][dd]);
            vt[1] = cvt_pk(va[2][dd], va[3][dd]);
            *(u32x2*)((char*)Vb + swzV(d0 + dd, kc * 2)) = vt;
        }
    };

    const int qg = iq * QBLK + w * 16 + l16;
    bf16x8 qf[2];
    {
        const float* qp = Q + bhoff + (size_t)qg * rs_ + lhi * 8;
        #pragma unroll
        for (int kf = 0; kf < 2; ++kf) {
            f32x4 xv = *(const f32x4*)(qp + kf * 32);
            f32x4 yv = *(const f32x4*)(qp + kf * 32 + 4);
            union { u32x4 u; bf16x8 hh; } r;
            r.u[0] = cvt_pk(xv[0] * QSC, xv[1] * QSC);
            r.u[1] = cvt_pk(xv[2] * QSC, xv[3] * QSC);
            r.u[2] = cvt_pk(yv[0] * QSC, yv[1] * QSC);
            r.u[3] = cvt_pk(yv[2] * QSC, yv[3] * QSC);
            qf[kf] = r.hh;
        }
    }

    float m_run = -INFINITY, lsum = 0.0f;
    f32x4 oacc[4];
    #pragma unroll
    for (int dt = 0; dt < 4; ++dt) oacc[dt] = (f32x4){0.f, 0.f, 0.f, 0.f};

    const int total = iq + 1;
    issue_loads(0);
    write_lds(0);
    if (total > 1) issue_loads(1);
    __syncthreads();

    for (int i = 0; i < total; ++i) {
        const char* Kbl = (const char*)Kl[i & 1];
        const char* Vbl = (const char*)Vl[i & 1];
        f32x4 p[4];
        #pragma unroll
        for (int st = 0; st < 4; ++st) p[st] = (f32x4){0.f, 0.f, 0.f, 0.f};
        __builtin_amdgcn_s_setprio(1);
        #pragma unroll
        for (int st = 0; st < 4; ++st) {
            #pragma unroll
            for (int kf = 0; kf < 2; ++kf) {
                bf16x8 af = *(const bf16x8*)(Kbl + swz(st * 16 + l16, (lhi * 8 + kf * 32) * 2));
                p[st] = __builtin_amdgcn_mfma_f32_16x16x32_bf16(af, qf[kf], p[st], 0, 0, 0);
            }
        }
        __builtin_amdgcn_s_setprio(0);
        if (i == total - 1) {
            #pragma unroll
            for (int st = 0; st < 4; ++st)
                #pragma unroll
                for (int r = 0; r < 4; ++r) {
                    const int kg = i * KVBLK + st * 16 + lhi * 4 + r;
                    if (kg > qg) p[st][r] = -INFINITY;
                }
        }
        if (i + 1 < total) write_lds((i + 1) & 1);
        if (i + 2 < total) issue_loads(i + 2);

        f32x4 mv = p[0];
        #pragma unroll
        for (int st = 1; st < 4; ++st)
            #pragma unroll
            for (int r = 0; r < 4; ++r) mv[r] = fmaxf(mv[r], p[st][r]);
        float mx = fmaxf(fmaxf(mv[0], mv[1]), fmaxf(mv[2], mv[3]));
        mx = gmax4(mx);
        if (!__all(mx <= m_run + THR)) {
            const float mn = fmaxf(m_run, mx);
            const float corr = fexp2(m_run - mn);
            lsum *= corr;
            #pragma unroll
            for (int dt = 0; dt < 4; ++dt)
                #pragma unroll
                for (int r = 0; r < 4; ++r) oacc[dt][r] *= corr;
            m_run = mn;
        }
        f32x4 rsv = (f32x4){0.f, 0.f, 0.f, 0.f};
        #pragma unroll
        for (int st = 0; st < 4; ++st)
            #pragma unroll
            for (int r = 0; r < 4; ++r) {
                const float e = fexp2(p[st][r] - m_run);
                p[st][r] = e;
                rsv[r] += e;
            }
        lsum += gsum4((rsv[0] + rsv[1]) + (rsv[2] + rsv[3]));

        unsigned wp[4][2];
        #pragma unroll
        for (int st = 0; st < 4; ++st) {
            wp[st][0] = cvt_pk(p[st][0], p[st][1]);
            wp[st][1] = cvt_pk(p[st][2], p[st][3]);
        }
        #pragma unroll
        for (int hh = 0; hh < 2; ++hh) {
            pl16(wp[0][hh], wp[1][hh]);
            pl16(wp[2][hh], wp[3][hh]);
            pl32(wp[0][hh], wp[2][hh]);
            pl32(wp[1][hh], wp[3][hh]);
        }
        union { u32x4 u; bf16x8 v; } pb0, pb1;
        pb0.u[0] = wp[0][0]; pb0.u[1] = wp[0][1];
        pb0.u[2] = wp[1][0]; pb0.u[3] = wp[1][1];
        pb1.u[0] = wp[2][0]; pb1.u[1] = wp[2][1];
        pb1.u[2] = wp[3][0]; pb1.u[3] = wp[3][1];

        __builtin_amdgcn_s_setprio(1);
        #pragma unroll
        for (int dt = 0; dt < 4; ++dt) {
            bf16x8 vf0 = *(const bf16x8*)(Vbl + swzV(dt * 16 + l16, (lhi * 8) * 2));
            oacc[dt] = __builtin_amdgcn_mfma_f32_16x16x32_bf16(vf0, pb0.v, oacc[dt], 0, 0, 0);
            bf16x8 vf1 = *(const bf16x8*)(Vbl + swzV(dt * 16 + l16, (lhi * 8 + 32) * 2));
            oacc[dt] = __builtin_amdgcn_mfma_f32_16x16x32_bf16(vf1, pb1.v, oacc[dt], 0, 0, 0);
        }
        __builtin_amdgcn_s_setprio(0);
        if (i + 1 < total) __syncthreads();
    }

    const float inv = 1.0f / lsum;
    float* op = O + bhoff + (size_t)qg * rs_;
    #pragma unroll
    for (int dt = 0; dt < 4; ++dt) {
        f32x4 o = oacc[dt];
        o[0] *= inv; o[1] *= inv; o[2] *= inv; o[3] *= inv;
        *(f32x4*)(op + dt * 16 + lhi * 4) = o;
    }
}

extern "C" void kernel_launch(void* const* d_in, const int* in_sizes, int n_in,
                              void* d_out, int out_size, void* d_ws, size_t ws_size,
                              hipStream_t stream) {
    const float* Q = (const float*)d_in[0];
    const float* K = (const float*)d_in[1];
    const float* V = (const float*)d_in[2];
    float* O = (float*)d_out;
    const size_t kb_elems = (size_t)32 * 32 * 4096;   // 4M shorts = 8MB
    if (ws_size >= 2 * kb_elems * sizeof(short)) {
        short* Kb = (short*)d_ws;
        short* Vb = Kb + kb_elems;
        prep_kernel<<<1024, 256, 0, stream>>>(K, V, Kb, Vb);
        fattn_main<<<1024, 256, 0, stream>>>(Q, Kb, Vb, O);
    } else {
        fattn_fb<<<1024, 256, 0, stream>>>(Q, K, V, O);
    }
}